// Round 18
// baseline (134.504 us; speedup 1.0000x reference)
//
#include <hip/hip_runtime.h>
#include <stdint.h>

// ---------------------------------------------------------------------------
// MultiHeadSelfAttention: x(2,2048,1024) fp32, w_qkv(1024,3072), w_out(1024,1024)
// R17: R16's 64^2 qkv regressed (occ 56% but intensity halved -> L2/issue
// bound, 65us). Interpolate: qkv on 128x64 tile — A-panel structure of 128^2
// (A traffic unchanged) + grid 1536 -> 4 blocks/CU (LDS 36KB). Same proven
// distance-2 / 3-buffer / counted-vmcnt(3) schedule. Out-proj stays 64^2
// (proven 12us at 4/CU), attn/prep unchanged (R15 config).
// ---------------------------------------------------------------------------

#define B_ 2
#define T_ 2048
#define C_ 1024
#define H_ 16
#define D_ 64
#define F_ 3072
#define M_ 4096

typedef unsigned short u16;
typedef unsigned int u32;
typedef u16 u16x2 __attribute__((ext_vector_type(2)));
typedef u16 u16x4 __attribute__((ext_vector_type(4)));
typedef u16 u16x8 __attribute__((ext_vector_type(8)));
typedef __bf16 bf16x8 __attribute__((ext_vector_type(8)));
typedef float f32x4 __attribute__((ext_vector_type(4)));

#define AS1 __attribute__((address_space(1)))
#define AS3 __attribute__((address_space(3)))

__device__ __forceinline__ float b2f(u16 u) {
  union { unsigned int i; float f; } v; v.i = ((unsigned int)u) << 16; return v.f;
}
__device__ __forceinline__ u16 f2b(float f) {  // RNE, finite inputs
  unsigned int u = __float_as_uint(f);
  u += 0x7fffu + ((u >> 16) & 1u);
  return (u16)(u >> 16);
}
__device__ __forceinline__ bf16x8 u2b8(u16x8 v) {
  union { u16x8 u; bf16x8 b; } x; x.u = v; return x.b;
}

// ----------------------------- fused prep kernel ---------------------------
// grid 8448 x 256: [0,4096) cast_x | [4096,7168) transpose w_qkv |
// [7168,8192) transpose w_out | [8192,8448) rope cos/sin table.
__global__ __launch_bounds__(256) void prep_kernel(const float* __restrict__ x,
                                                   const float* __restrict__ w_qkv,
                                                   const float* __restrict__ w_out,
                                                   u16* __restrict__ xb,
                                                   u16* __restrict__ wqkvT,
                                                   u16* __restrict__ woutT,
                                                   float2* __restrict__ csT) {
  __shared__ float tile[32][33];
  const int bid = blockIdx.x;
  const int tid = threadIdx.x;

  if (bid < 4096) {                       // ---- cast_x: fp32 -> bf16 ----
    int i = bid * 256 + tid;              // M_*C_/4 elems of float4
    float4 v = ((const float4*)x)[i];
    u16x4 r;
    r[0] = f2b(v.x); r[1] = f2b(v.y); r[2] = f2b(v.z); r[3] = f2b(v.w);
    ((u16x4*)xb)[i] = r;
  } else if (bid < 8192) {                // ---- transpose_cast w_qkv / w_out
    const float* in;  u16* out;  int R, Ccol, b;
    if (bid < 7168) { in = w_qkv; out = wqkvT; R = C_; Ccol = F_; b = bid - 4096; }
    else            { in = w_out; out = woutT; R = C_; Ccol = C_; b = bid - 7168; }
    int nbx = Ccol / 32;
    int c0 = (b % nbx) * 32, r0 = (b / nbx) * 32;
    int tx = tid & 31, ty = tid >> 5;     // ty = 0..7
    #pragma unroll
    for (int i = 0; i < 32; i += 8)
      tile[ty + i][tx] = in[(size_t)(r0 + ty + i) * Ccol + c0 + tx];
    __syncthreads();
    #pragma unroll
    for (int i = 0; i < 32; i += 8)
      out[(size_t)(c0 + ty + i) * R + r0 + tx] = f2b(tile[tx][ty + i]);
  } else {                                // ---- rope table ----
    int idx = (bid - 8192) * 256 + tid;   // T_*32 entries
    int t = idx >> 5, i = idx & 31;
    float inv_freq = powf(10000.0f, -(float)(2 * i) / 64.0f);
    float ang = (float)t * inv_freq;
    csT[idx] = make_float2(cosf(ang), sinf(ang));
  }
}

// ----------------------- MFMA GEMM (128x64, QKV+RoPE) ----------------------
// C[4096,3072] = xb x wqkvT^T. BM=128, BN=64, BK=32. 4 waves as 2x2; wave tile
// 64x32 = 4x2 frags (8 MFMA/k-step). Staging: A 2 DMA/thread, B 1 DMA/thread
// -> vmcnt(3) (distance-2: leave newest tile's 3 in flight). LDS 36KB -> 4
// blocks/CU; grid (48,32)=1536 (%8==0, bijective XCD swizzle).
// Epilogue: RoPE scatter (block maps to one head; d0 = wc*32+n*16+l16).
__global__ __launch_bounds__(256) void gemm_qkv_kernel(const u16* __restrict__ A,
                                                       const u16* __restrict__ Bt,
                                                       u16* __restrict__ qr,
                                                       u16* __restrict__ kr,
                                                       u16* __restrict__ vrp,
                                                       const float2* __restrict__ csT) {
  __shared__ u16 sA[3][128 * 32];
  __shared__ u16 sB[3][64 * 32];
  const int tid = threadIdx.x;
  const int lane = tid & 63;
  const int wv = tid >> 6;
  const int wr = wv >> 1, wc = wv & 1;
  const int l16 = lane & 15, lq = lane >> 4;
  const int K = 1024;

  const int gx = 48;                     // N/64
  const int nwg = 1536;
  const int flat = blockIdx.y * gx + blockIdx.x;
  const int swz = (flat & 7) * (nwg >> 3) + (flat >> 3);
  const int rowBase = (swz / gx) * 128;
  const int colBase = (swz % gx) * 64;

  f32x4 acc[4][2] = {};

  const int ea = wv * 1024 + lane * 8;   // A elem offset (4096/tile, 2 chunks)
  const int eb = wv * 512 + lane * 8;    // B elem offset (2048/tile, 1 chunk)

#define GSTAGE(buf, kk)                                                          \
  {                                                                              \
    _Pragma("unroll")                                                            \
    for (int s = 0; s < 2; ++s) {                                                \
      int e = ea + s * 512;                                                      \
      int r = e >> 5, ccc = e & 31;                                              \
      __builtin_amdgcn_global_load_lds(                                          \
          (const AS1 u32*)(A + (size_t)(rowBase + r) * K + (kk) + ccc),          \
          (AS3 u32*)&sA[buf][wv * 1024 + s * 512], 16, 0, 0);                    \
    }                                                                            \
    {                                                                            \
      int r = eb >> 5, ccc = eb & 31;                                            \
      __builtin_amdgcn_global_load_lds(                                          \
          (const AS1 u32*)(Bt + (size_t)(colBase + r) * K + (kk) + ccc),         \
          (AS3 u32*)&sB[buf][wv * 512], 16, 0, 0);                               \
    }                                                                            \
  }

  const int NT = 32;                     // K/32
  GSTAGE(0, 0);
  GSTAGE(1, 32);

  int cur = 0;
  for (int kt = 0; kt < NT; ++kt) {
    if (kt + 1 < NT) {
      asm volatile("s_waitcnt vmcnt(3)" ::: "memory");   // tile kt landed (own 3)
    } else {
      asm volatile("s_waitcnt vmcnt(0)" ::: "memory");   // final tile
    }
    __builtin_amdgcn_s_barrier();        // tile kt visible; kt-1 reads done

    if (kt + 2 < NT) {
      int nb = cur + 2; if (nb >= 3) nb -= 3;
      GSTAGE(nb, (kt + 2) * 32);         // overlaps this iter's compute
    }

    bf16x8 af[4], bf[2];
    #pragma unroll
    for (int m = 0; m < 4; ++m)
      af[m] = u2b8(*(const u16x8*)&sA[cur][(wr * 64 + m * 16 + l16) * 32 + lq * 8]);
    #pragma unroll
    for (int n = 0; n < 2; ++n)
      bf[n] = u2b8(*(const u16x8*)&sB[cur][(wc * 32 + n * 16 + l16) * 32 + lq * 8]);
    __builtin_amdgcn_s_setprio(1);
    #pragma unroll
    for (int m = 0; m < 4; ++m)
      #pragma unroll
      for (int n = 0; n < 2; ++n)
        acc[m][n] = __builtin_amdgcn_mfma_f32_16x16x32_bf16(af[m], bf[n], acc[m][n], 0, 0, 0);
    __builtin_amdgcn_s_setprio(0);

    cur = (cur + 1 == 3) ? 0 : cur + 1;
  }
#undef GSTAGE

  // RoPE epilogue (C/D: col=l16, row=lq*4+j; verified)
  const int which = colBase >> 10;                 // block-uniform
  const int head = (colBase >> 6) & 15;
  const float QSC = 0.125f * 1.44269504f;
  u16* const dst = (which == 0) ? qr : (which == 1) ? kr : vrp;
  #pragma unroll
  for (int m = 0; m < 4; ++m) {
    #pragma unroll
    for (int n = 0; n < 2; ++n) {
      const int d0 = wc * 32 + n * 16 + l16;       // d within head (0..63)
      #pragma unroll
      for (int j = 0; j < 4; ++j) {
        int row = rowBase + wr * 64 + m * 16 + lq * 4 + j;
        int b = row >> 11, t = row & 2047;
        float v = acc[m][n][j];
        u16 outv;
        if (which == 2) {
          outv = f2b(v);
        } else {
          float p = __shfl_xor(v, 1);              // RoPE partner (d0^1)
          float2 cs = csT[t * 32 + (d0 >> 1)];
          float r = (l16 & 1) ? fmaf(p, cs.y, v * cs.x)    // odd:  xe*s + xo*c
                              : fmaf(-p, cs.y, v * cs.x);  // even: xe*c - xo*s
          if (which == 0) r *= QSC;
          outv = f2b(r);
        }
        dst[((size_t)(b * 16 + head) * 2048 + t) * 64 + d0] = outv;
      }
    }
  }
}

// --------------------------- MFMA GEMM (64^2, out-proj) --------------------
// C[M,N] = A[M,K] * Bt[N,K]^T, float out. 64x64 tile, BK=32, 4 waves (2x2,
// each 32x32 = 2x2 frags), distance-2 / 3-buffer / vmcnt(2). grid (16,64) =
// 1024 blocks = 4 blocks/CU. LDS 24KB. XCD swizzle (1024%8==0). (R15-proven)
__global__ __launch_bounds__(256) void gemm64_kernel(const u16* __restrict__ A,
                                                     const u16* __restrict__ Bt,
                                                     float* __restrict__ Cm,
                                                     int M, int N, int K) {
  __shared__ u16 sA[3][64 * 32];
  __shared__ u16 sB[3][64 * 32];
  const int tid = threadIdx.x;
  const int lane = tid & 63;
  const int wv = tid >> 6;
  const int wr = wv >> 1, wc = wv & 1;
  const int l16 = lane & 15, lq = lane >> 4;

  const int gx = gridDim.x;
  const int nwg = gx * gridDim.y;
  const int flat = blockIdx.y * gx + blockIdx.x;
  const int swz = (flat & 7) * (nwg >> 3) + (flat >> 3);
  const int rowBase = (swz / gx) * 64;
  const int colBase = (swz % gx) * 64;

  f32x4 acc[2][2] = {};

  const int e0 = wv * 512 + lane * 8;       // this lane's elem offset (2048/tile)

#define GSTAGE64(buf, kk)                                                        \
  {                                                                              \
    int r = e0 >> 5, ccc = e0 & 31;                                              \
    __builtin_amdgcn_global_load_lds(                                            \
        (const AS1 u32*)(A + (size_t)(rowBase + r) * K + (kk) + ccc),            \
        (AS3 u32*)&sA[buf][wv * 512], 16, 0, 0);                                 \
    __builtin_amdgcn_global_load_lds(                                            \
        (const AS1 u32*)(Bt + (size_t)(colBase + r) * K + (kk) + ccc),           \
        (AS3 u32*)&sB[buf][wv * 512], 16, 0, 0);                                 \
  }

  const int NT = K >> 5;                 // K/32 tiles
  GSTAGE64(0, 0);
  if (NT > 1) GSTAGE64(1, 32);

  int cur = 0;
  for (int kt = 0; kt < NT; ++kt) {
    if (kt + 1 < NT) {
      asm volatile("s_waitcnt vmcnt(2)" ::: "memory");   // tile kt landed (own 2)
    } else {
      asm volatile("s_waitcnt vmcnt(0)" ::: "memory");   // final tile
    }
    __builtin_amdgcn_s_barrier();        // tile kt visible; kt-1 reads done

    if (kt + 2 < NT) {
      int nb = cur + 2; if (nb >= 3) nb -= 3;
      GSTAGE64(nb, (kt + 2) * 32);       // overlaps this iter's compute
    }

    bf16x8 af[2], bf[2];
    #pragma unroll
    for (int m = 0; m < 2; ++m)
      af[m] = u2b8(*(const u16x8*)&sA[cur][(wr * 32 + m * 16 + l16) * 32 + lq * 8]);
    #pragma unroll
    for (int n = 0; n < 2; ++n)
      bf[n] = u2b8(*(const u16x8*)&sB[cur][(wc * 32 + n * 16 + l16) * 32 + lq * 8]);
    __builtin_amdgcn_s_setprio(1);
    #pragma unroll
    for (int m = 0; m < 2; ++m)
      #pragma unroll
      for (int n = 0; n < 2; ++n)
        acc[m][n] = __builtin_amdgcn_mfma_f32_16x16x32_bf16(af[m], bf[n], acc[m][n], 0, 0, 0);
    __builtin_amdgcn_s_setprio(0);

    cur = (cur + 1 == 3) ? 0 : cur + 1;
  }
#undef GSTAGE64

  // C/D layout: col = lane&15, row = (lane>>4)*4 + reg
  #pragma unroll
  for (int m = 0; m < 2; ++m)
    #pragma unroll
    for (int n = 0; n < 2; ++n) {
      int row = rowBase + wr * 32 + m * 16 + lq * 4;
      int col = colBase + wc * 32 + n * 16 + l16;
      #pragma unroll
      for (int j = 0; j < 4; ++j)
        Cm[(size_t)(row + j) * N + col] = acc[m][n][j];
    }
}

// ------------------------- MFMA flash attention ----------------------------
// R9 config (proven fastest): 16 q-rows/wave, grid (32,32) descending, swapped
// QK^T, in-register P via k-slot permutation (V rows staged bit-permuted
// vrow=[b5 b2 b4 b3 b1 b0] so PV A-operand = own exp2'd registers), K staged
// by global_load_lds DMA into linear [64][64] with chunk swizzle (slot (r,c)
// holds chunk c^(r&7)), double buffer, T14 prefetch, ONE barrier per tile.
__global__ __launch_bounds__(256, 4) void attn_mfma_kernel(const u16* __restrict__ qr,
                                                           const u16* __restrict__ kr,
                                                           const u16* __restrict__ vr,
                                                           u16* __restrict__ ao) {
  constexpr int LDVT = 72;
  __shared__ u16 sK[2][64 * 64];                 // linear, chunk-swizzled
  __shared__ u16 sVt[2][64 * LDVT];              // sVt[buf][d][k-slot]

  const int tid = threadIdx.x;
  const int lane = tid & 63;
  const int w = tid >> 6;
  const int l16 = lane & 15, lq = lane >> 4;
  const int bh = blockIdx.x;
  const int qt = (int)gridDim.y - 1 - (int)blockIdx.y;   // long blocks first
  const int qbase = qt * 64;
  const size_t hb = (size_t)bh * (T_ * D_);

  // Q frags (pre-scaled bf16): rows qbase + w*16 + l16
  bf16x8 qv[2];
  #pragma unroll
  for (int dc = 0; dc < 2; ++dc) {
    int row = qbase + w * 16 + l16;
    qv[dc] = u2b8(*(const u16x8*)(qr + hb + (size_t)row * 64 + dc * 32 + lq * 8));
  }

  f32x4 o[4] = {};              // o[dt]: O[q=lq*4+j][d=dt*16+l16]
  float mrow = -1e30f;          // running max (log2 domain), row q=l16
  float lrow = 0.0f;            // per-lane partial denom, row q=l16

  // K DMA maps: wave w covers rows w*16 + s*8 + (lane>>3), chunk lane&7.
  const int krow0 = w * 16 + (lane >> 3);
  const int ksrc = ((lane & 7) ^ (lane >> 3)) * 8;   // elem offset in row
  // V staging maps (reg path)
  const int vkp = tid & 31;           // V slot-pair 0..31 (slots 2vkp, 2vkp+1)
  const int vdb = tid >> 5;           // V d-block 0..7
  const int vtr = ((vkp >> 4) & 1) * 32 + ((vkp >> 1) & 1) * 16 +
                  ((vkp >> 3) & 1) * 8 + ((vkp >> 2) & 1) * 4 + (vkp & 1) * 2;

  u16x8 rv0, rv1;
#define STAGEK(buf, k0s)                                                       \
  {                                                                            \
    _Pragma("unroll")                                                          \
    for (int s = 0; s < 2; ++s)                                                \
      __builtin_amdgcn_global_load_lds(                                        \
          (const AS1 u32*)(kr + hb + (size_t)((k0s) + krow0 + s * 8) * 64 + ksrc), \
          (AS3 u32*)&sK[buf][(w * 16 + s * 8) * 64], 16, 0, 0);                \
  }
#define LOADV(k0s)                                                             \
  {                                                                            \
    rv0 = *(const u16x8*)(vr + hb + (size_t)((k0s) + vtr) * 64 + vdb * 8);     \
    rv1 = *(const u16x8*)(vr + hb + (size_t)((k0s) + vtr + 1) * 64 + vdb * 8); \
  }
#define WRITEV(buf)                                                            \
  {                                                                            \
    _Pragma("unroll")                                                          \
    for (int u = 0; u < 8; ++u) {                                              \
      u16x2 pk; pk[0] = rv0[u]; pk[1] = rv1[u];                                \
      *(u16x2*)&sVt[buf][(vdb * 8 + u) * LDVT + 2 * vkp] = pk;                 \
    }                                                                          \
  }

  STAGEK(0, 0);
  LOADV(0);
  WRITEV(0);
  __syncthreads();               // drains vmcnt (K DMA) + LDS writes

  const int nt = qt + 1;
  int cur = 0;
  for (int it = 0; it < nt; ++it) {
    const int k0 = it * 64;
    const bool more = (it + 1 < nt);
    if (more) {
      STAGEK(cur ^ 1, k0 + 64);        // async DMA into other buffer
      LOADV(k0 + 64);                  // V prefetch into regs (T14)
    }

    // ---- QK^T (swapped): accs[kt][j] = S[q=l16][slot k0+kt*16+lq*4+j]
    f32x4 accs[4] = {};
    __builtin_amdgcn_s_setprio(1);
    #pragma unroll
    for (int kt = 0; kt < 4; ++kt) {
      int chy = ((lq) ^ (l16 & 7)) * 8;        // dc=0 chunk
      int chz = ((4 + lq) ^ (l16 & 7)) * 8;    // dc=1 chunk
      bf16x8 kf0 = u2b8(*(const u16x8*)&sK[cur][(kt * 16 + l16) * 64 + chy]);
      bf16x8 kf1 = u2b8(*(const u16x8*)&sK[cur][(kt * 16 + l16) * 64 + chz]);
      accs[kt] = __builtin_amdgcn_mfma_f32_16x16x32_bf16(kf0, qv[0], accs[kt], 0, 0, 0);
      accs[kt] = __builtin_amdgcn_mfma_f32_16x16x32_bf16(kf1, qv[1], accs[kt], 0, 0, 0);
    }
    __builtin_amdgcn_s_setprio(0);

    const int qrow = qbase + w * 16 + l16;
    if (k0 + 63 > qbase + w * 16) {      // wave-uniform: diagonal tile only
      #pragma unroll
      for (int kt = 0; kt < 4; ++kt)
        #pragma unroll
        for (int j = 0; j < 4; ++j)
          if (k0 + kt * 16 + lq * 4 + j > qrow) accs[kt][j] = -1e30f;
    }
    // row max for q=l16: depth-4 tree + 2 shfl (k spread across lq groups)
    float m0 = fmaxf(fmaxf(accs[0][0], accs[0][1]), fmaxf(accs[0][2], accs[0][3]));
    float m1 = fmaxf(fmaxf(accs[1][0], accs[1][1]), fmaxf(accs[1][2], accs[1][3]));
    float m2 = fmaxf(fmaxf(accs[2][0], accs[2][1]), fmaxf(accs[2][2], accs[2][3]));
    float m3 = fmaxf(fmaxf(accs[3][0], accs[3][1]), fmaxf(accs[3][2], accs[3][3]));
    float mx = fmaxf(fmaxf(m0, m1), fmaxf(m2, m3));
    mx = fmaxf(mx, __shfl_xor(mx, 16));
    mx = fmaxf(mx, __shfl_xor(mx, 32));

    if (!__all(mx <= mrow)) {            // defer-max: exact skip when no new max
      float mnew = fmaxf(mrow, mx);
      float corr = __builtin_amdgcn_exp2f(mrow - mnew);   // row q=l16
      lrow *= corr;
      mrow = mnew;
      // broadcast corr into D-row space (q=lq*4+j) before scaling O
      f32x4 corrv;
      #pragma unroll
      for (int j = 0; j < 4; ++j) corrv[j] = __shfl(corr, lq * 4 + j);
      #pragma unroll
      for (int dt = 0; dt < 4; ++dt) o[dt] *= corrv;
    }
    const float mu = mrow;
    // exp2 + pack: pb[kc][u] : u<4 <- slot kt=2kc, u>=4 <- kt=2kc+1
    bf16x8 pb[2];
    float lsum = 0.0f;
    #pragma unroll
    for (int kt = 0; kt < 4; ++kt) {
      #pragma unroll
      for (int j = 0; j < 4; ++j) {
        float p = __builtin_amdgcn_exp2f(accs[kt][j] - mu);
        lsum += p;
        pb[kt >> 1][(kt & 1) * 4 + j] = (__bf16)p;   // -> v_cvt_pk_bf16_f32
      }
    }
    lrow += lsum;

    // ---- PV: A-operand = own registers (slot perm); B from sVt ----
    __builtin_amdgcn_s_setprio(1);
    #pragma unroll
    for (int kc = 0; kc < 2; ++kc) {
      #pragma unroll
      for (int dt = 0; dt < 4; ++dt) {
        bf16x8 vt = u2b8(*(const u16x8*)&sVt[cur][(dt * 16 + l16) * LDVT + kc * 32 + lq * 8]);
        o[dt] = __builtin_amdgcn_mfma_f32_16x16x32_bf16(pb[kc], vt, o[dt], 0, 0, 0);
      }
    }
    __builtin_amdgcn_s_setprio(0);

    if (more) WRITEV(cur ^ 1);           // V^T into other buffer (reads were cur)
    __syncthreads();                     // one barrier/tile; drains K DMA too
    cur ^= 1;
  }

  // finalize: full row denom in l16-space, broadcast 1/l into D-row space.
  const int b = bh >> 4, h = bh & 15;
  float l = lrow;
  l += __shfl_xor(l, 16);
  l += __shfl_xor(l, 32);
  float linv = 1.0f / l;
  #pragma unroll
  for (int j = 0; j < 4; ++j) {
    float lj = __shfl(linv, lq * 4 + j);   // lane r (r<16) holds row r's denom
    int row = qbase + w * 16 + lq * 4 + j;
    u16* orow = ao + ((size_t)(b * T_ + row)) * C_ + h * 64;
    #pragma unroll
    for (int dt = 0; dt < 4; ++dt)
      orow[dt * 16 + l16] = f2b(o[dt][j] * lj);
  }
}

// ------------------------------- launcher ----------------------------------
// ws layout (bytes):                              size
//   xb     @ 0           bf16 x           8,388,608
//   wqkvT  @ 8388608     bf16 w_qkv^T     6,291,456
//   woutT  @ 14680064    bf16 w_out^T     2,097,152
//   qr     @ 41943040    bf16 [B,H,T,D]   8,388,608
//   kr     @ 50331648                     8,388,608
//   vr     @ 58720256                     8,388,608
//   ao     @ 67108864    bf16 attn out    8,388,608
//   csT    @ 75497472    f32x2 rope tbl     524,288
extern "C" void kernel_launch(void* const* d_in, const int* in_sizes, int n_in,
                              void* d_out, int out_size, void* d_ws, size_t ws_size,
                              hipStream_t stream) {
  const float* x     = (const float*)d_in[0];
  const float* w_qkv = (const float*)d_in[1];
  const float* w_out = (const float*)d_in[2];
  float* out = (float*)d_out;
  char* ws = (char*)d_ws;

  u16* xb     = (u16*)(ws + 0);
  u16* wqkvT  = (u16*)(ws + 8388608);
  u16* woutT  = (u16*)(ws + 14680064);
  u16* qr     = (u16*)(ws + 41943040);
  u16* kr     = (u16*)(ws + 50331648);
  u16* vr     = (u16*)(ws + 58720256);
  u16* ao     = (u16*)(ws + 67108864);
  float2* csT = (float2*)(ws + 75497472);

  prep_kernel<<<8448, 256, 0, stream>>>(x, w_qkv, w_out, xb, wqkvT, woutT, csT);
  gemm_qkv_kernel<<<dim3(48, 32), 256, 0, stream>>>(xb, wqkvT, qr, kr, vr, (const float2*)csT);
  attn_mfma_kernel<<<dim3(B_ * H_, T_ / 64), 256, 0, stream>>>(qr, kr, vr, ao);
  gemm64_kernel<<<dim3(C_ / 64, M_ / 64), 256, 0, stream>>>(ao, woutT, out, M_, C_, C_);
}

// Round 19
// 121.714 us; speedup vs baseline: 1.1051x; 1.1051x over previous
//
#include <hip/hip_runtime.h>
#include <stdint.h>

// ---------------------------------------------------------------------------
// MultiHeadSelfAttention: x(2,2048,1024) fp32, w_qkv(1024,3072), w_out(1024,1024)
// R18: restore R15 exactly (measured best, 121.5us). Tile-scan ledger closed:
// qkv 128^2=51us beats 64^2 (65) and 128x64 (65) — intensity beats occupancy
// once >=3 blocks/CU; out-proj 64^2 (1->4 blocks/CU) = 11.5us; attn R9 16q/wave
// (4 restructures all regressed); prep fused. 10.3x over R0 baseline.
// ---------------------------------------------------------------------------

#define B_ 2
#define T_ 2048
#define C_ 1024
#define H_ 16
#define D_ 64
#define F_ 3072
#define M_ 4096

typedef unsigned short u16;
typedef unsigned int u32;
typedef u16 u16x2 __attribute__((ext_vector_type(2)));
typedef u16 u16x4 __attribute__((ext_vector_type(4)));
typedef u16 u16x8 __attribute__((ext_vector_type(8)));
typedef __bf16 bf16x8 __attribute__((ext_vector_type(8)));
typedef float f32x4 __attribute__((ext_vector_type(4)));

#define AS1 __attribute__((address_space(1)))
#define AS3 __attribute__((address_space(3)))

__device__ __forceinline__ float b2f(u16 u) {
  union { unsigned int i; float f; } v; v.i = ((unsigned int)u) << 16; return v.f;
}
__device__ __forceinline__ u16 f2b(float f) {  // RNE, finite inputs
  unsigned int u = __float_as_uint(f);
  u += 0x7fffu + ((u >> 16) & 1u);
  return (u16)(u >> 16);
}
__device__ __forceinline__ bf16x8 u2b8(u16x8 v) {
  union { u16x8 u; bf16x8 b; } x; x.u = v; return x.b;
}

// ----------------------------- fused prep kernel ---------------------------
// grid 8448 x 256: [0,4096) cast_x | [4096,7168) transpose w_qkv |
// [7168,8192) transpose w_out | [8192,8448) rope cos/sin table.
__global__ __launch_bounds__(256) void prep_kernel(const float* __restrict__ x,
                                                   const float* __restrict__ w_qkv,
                                                   const float* __restrict__ w_out,
                                                   u16* __restrict__ xb,
                                                   u16* __restrict__ wqkvT,
                                                   u16* __restrict__ woutT,
                                                   float2* __restrict__ csT) {
  __shared__ float tile[32][33];
  const int bid = blockIdx.x;
  const int tid = threadIdx.x;

  if (bid < 4096) {                       // ---- cast_x: fp32 -> bf16 ----
    int i = bid * 256 + tid;              // M_*C_/4 elems of float4
    float4 v = ((const float4*)x)[i];
    u16x4 r;
    r[0] = f2b(v.x); r[1] = f2b(v.y); r[2] = f2b(v.z); r[3] = f2b(v.w);
    ((u16x4*)xb)[i] = r;
  } else if (bid < 8192) {                // ---- transpose_cast w_qkv / w_out
    const float* in;  u16* out;  int R, Ccol, b;
    if (bid < 7168) { in = w_qkv; out = wqkvT; R = C_; Ccol = F_; b = bid - 4096; }
    else            { in = w_out; out = woutT; R = C_; Ccol = C_; b = bid - 7168; }
    int nbx = Ccol / 32;
    int c0 = (b % nbx) * 32, r0 = (b / nbx) * 32;
    int tx = tid & 31, ty = tid >> 5;     // ty = 0..7
    #pragma unroll
    for (int i = 0; i < 32; i += 8)
      tile[ty + i][tx] = in[(size_t)(r0 + ty + i) * Ccol + c0 + tx];
    __syncthreads();
    #pragma unroll
    for (int i = 0; i < 32; i += 8)
      out[(size_t)(c0 + ty + i) * R + r0 + tx] = f2b(tile[tx][ty + i]);
  } else {                                // ---- rope table ----
    int idx = (bid - 8192) * 256 + tid;   // T_*32 entries
    int t = idx >> 5, i = idx & 31;
    float inv_freq = powf(10000.0f, -(float)(2 * i) / 64.0f);
    float ang = (float)t * inv_freq;
    csT[idx] = make_float2(cosf(ang), sinf(ang));
  }
}

// ------------------------------- MFMA GEMM (128^2) -------------------------
// C[M,N] = A[M,K] * Bt[N,K]^T, bf16 in. 128x128 tile, BK=32, 4 waves, 4x4
// 16x16x32 frags, global_load_lds(16) staging, 3-buffer distance-2 pipeline,
// T1 bijective XCD swizzle.
// MODE 0: float out to Cm.
// MODE 2: QKV epilogue — RoPE(q,k via lane-pair shfl + csT) + scatter to
//         qr/kr/vr [B,H,T,D]; q pre-scaled by 0.125*log2(e).
template <int MODE>
__global__ __launch_bounds__(256) void gemm_bt_kernel(const u16* __restrict__ A,
                                                      const u16* __restrict__ Bt,
                                                      float* __restrict__ Cm,
                                                      u16* __restrict__ qr,
                                                      u16* __restrict__ kr,
                                                      u16* __restrict__ vrp,
                                                      const float2* __restrict__ csT,
                                                      int M, int N, int K) {
  __shared__ u16 sA[3][128 * 32];
  __shared__ u16 sB[3][128 * 32];
  const int tid = threadIdx.x;
  const int lane = tid & 63;
  const int wv = tid >> 6;
  const int wr = wv >> 1, wc = wv & 1;
  const int l16 = lane & 15, lq = lane >> 4;

  // T1 XCD swizzle: dispatch idx flat -> work item (flat%8)*cpx + flat/8.
  const int gx = gridDim.x;
  const int nwg = gx * gridDim.y;
  const int flat = blockIdx.y * gx + blockIdx.x;
  const int swz = (flat & 7) * (nwg >> 3) + (flat >> 3);
  const int rowBase = (swz / gx) * 128;
  const int colBase = (swz % gx) * 128;

  f32x4 acc[4][4] = {};

  const int e0 = wv * 1024 + lane * 8;      // this lane's elem offset, chunk 0

#define GSTAGE(buf, kk)                                                          \
  {                                                                              \
    _Pragma("unroll")                                                            \
    for (int s = 0; s < 2; ++s) {                                                \
      int e = e0 + s * 512;                                                      \
      int r = e >> 5, ccc = e & 31;                                              \
      __builtin_amdgcn_global_load_lds(                                          \
          (const AS1 u32*)(A + (size_t)(rowBase + r) * K + (kk) + ccc),          \
          (AS3 u32*)&sA[buf][wv * 1024 + s * 512], 16, 0, 0);                    \
      __builtin_amdgcn_global_load_lds(                                          \
          (const AS1 u32*)(Bt + (size_t)(colBase + r) * K + (kk) + ccc),         \
          (AS3 u32*)&sB[buf][wv * 1024 + s * 512], 16, 0, 0);                    \
    }                                                                            \
  }

  const int NT = K >> 5;                 // K/32 tiles
  GSTAGE(0, 0);
  if (NT > 1) GSTAGE(1, 32);

  int cur = 0;
  for (int kt = 0; kt < NT; ++kt) {
    if (kt + 1 < NT) {
      asm volatile("s_waitcnt vmcnt(4)" ::: "memory");   // tile kt landed (own)
    } else {
      asm volatile("s_waitcnt vmcnt(0)" ::: "memory");   // final tile
    }
    __builtin_amdgcn_s_barrier();        // tile kt visible; k-1 reads done

    if (kt + 2 < NT) {
      int nb = cur + 2; if (nb >= 3) nb -= 3;
      GSTAGE(nb, (kt + 2) * 32);         // overlaps this iter's compute
    }

    bf16x8 af[4], bf[4];
    #pragma unroll
    for (int m = 0; m < 4; ++m)
      af[m] = u2b8(*(const u16x8*)&sA[cur][(wr * 64 + m * 16 + l16) * 32 + lq * 8]);
    #pragma unroll
    for (int n = 0; n < 4; ++n)
      bf[n] = u2b8(*(const u16x8*)&sB[cur][(wc * 64 + n * 16 + l16) * 32 + lq * 8]);
    __builtin_amdgcn_s_setprio(1);
    #pragma unroll
    for (int m = 0; m < 4; ++m)
      #pragma unroll
      for (int n = 0; n < 4; ++n)
        acc[m][n] = __builtin_amdgcn_mfma_f32_16x16x32_bf16(af[m], bf[n], acc[m][n], 0, 0, 0);
    __builtin_amdgcn_s_setprio(0);

    cur = (cur + 1 == 3) ? 0 : cur + 1;
  }
#undef GSTAGE

  // C/D layout (verified m89): col = lane&15, row = (lane>>4)*4 + reg
  if constexpr (MODE == 0) {
    #pragma unroll
    for (int m = 0; m < 4; ++m)
      #pragma unroll
      for (int n = 0; n < 4; ++n) {
        int row = rowBase + wr * 64 + m * 16 + lq * 4;
        int col = colBase + wc * 64 + n * 16 + l16;
        #pragma unroll
        for (int j = 0; j < 4; ++j)
          Cm[(size_t)(row + j) * N + col] = acc[m][n][j];
      }
  } else {
    // which: 0=q 1=k 2=v (block-uniform); head: uniform per (wave,n-range)
    const int which = colBase >> 10;
    const int head = ((colBase + wc * 64) >> 6) & 15;
    const float QSC = 0.125f * 1.44269504f;
    u16* const dst = (which == 0) ? qr : (which == 1) ? kr : vrp;
    #pragma unroll
    for (int m = 0; m < 4; ++m) {
      #pragma unroll
      for (int n = 0; n < 4; ++n) {
        const int d0 = n * 16 + l16;           // d within head (0..63)
        #pragma unroll
        for (int j = 0; j < 4; ++j) {
          int row = rowBase + wr * 64 + m * 16 + lq * 4 + j;
          int b = row >> 11, t = row & 2047;
          float v = acc[m][n][j];
          u16 outv;
          if (which == 2) {
            outv = f2b(v);
          } else {
            float p = __shfl_xor(v, 1);        // RoPE partner (d0^1)
            float2 cs = csT[t * 32 + (d0 >> 1)];
            float r = (l16 & 1) ? fmaf(p, cs.y, v * cs.x)    // odd:  xe*s + xo*c
                                : fmaf(-p, cs.y, v * cs.x);  // even: xe*c - xo*s
            if (which == 0) r *= QSC;
            outv = f2b(r);
          }
          dst[((size_t)(b * 16 + head) * 2048 + t) * 64 + d0] = outv;
        }
      }
    }
  }
}

// --------------------------- MFMA GEMM (64^2, out-proj) --------------------
// C[M,N] = A[M,K] * Bt[N,K]^T, float out. 64x64 tile, BK=32, 4 waves (2x2,
// each 32x32 = 2x2 frags), distance-2 / 3-buffer / vmcnt(2). grid (16,64) =
// 1024 blocks = 4 blocks/CU. LDS 24KB. XCD swizzle (1024%8==0).
__global__ __launch_bounds__(256) void gemm64_kernel(const u16* __restrict__ A,
                                                     const u16* __restrict__ Bt,
                                                     float* __restrict__ Cm,
                                                     int M, int N, int K) {
  __shared__ u16 sA[3][64 * 32];
  __shared__ u16 sB[3][64 * 32];
  const int tid = threadIdx.x;
  const int lane = tid & 63;
  const int wv = tid >> 6;
  const int wr = wv >> 1, wc = wv & 1;
  const int l16 = lane & 15, lq = lane >> 4;

  const int gx = gridDim.x;
  const int nwg = gx * gridDim.y;
  const int flat = blockIdx.y * gx + blockIdx.x;
  const int swz = (flat & 7) * (nwg >> 3) + (flat >> 3);
  const int rowBase = (swz / gx) * 64;
  const int colBase = (swz % gx) * 64;

  f32x4 acc[2][2] = {};

  const int e0 = wv * 512 + lane * 8;       // this lane's elem offset (2048/tile)

#define GSTAGE64(buf, kk)                                                        \
  {                                                                              \
    int r = e0 >> 5, ccc = e0 & 31;                                              \
    __builtin_amdgcn_global_load_lds(                                            \
        (const AS1 u32*)(A + (size_t)(rowBase + r) * K + (kk) + ccc),            \
        (AS3 u32*)&sA[buf][wv * 512], 16, 0, 0);                                 \
    __builtin_amdgcn_global_load_lds(                                            \
        (const AS1 u32*)(Bt + (size_t)(colBase + r) * K + (kk) + ccc),           \
        (AS3 u32*)&sB[buf][wv * 512], 16, 0, 0);                                 \
  }

  const int NT = K >> 5;                 // K/32 tiles
  GSTAGE64(0, 0);
  if (NT > 1) GSTAGE64(1, 32);

  int cur = 0;
  for (int kt = 0; kt < NT; ++kt) {
    if (kt + 1 < NT) {
      asm volatile("s_waitcnt vmcnt(2)" ::: "memory");   // tile kt landed (own 2)
    } else {
      asm volatile("s_waitcnt vmcnt(0)" ::: "memory");   // final tile
    }
    __builtin_amdgcn_s_barrier();        // tile kt visible; kt-1 reads done

    if (kt + 2 < NT) {
      int nb = cur + 2; if (nb >= 3) nb -= 3;
      GSTAGE64(nb, (kt + 2) * 32);       // overlaps this iter's compute
    }

    bf16x8 af[2], bf[2];
    #pragma unroll
    for (int m = 0; m < 2; ++m)
      af[m] = u2b8(*(const u16x8*)&sA[cur][(wr * 32 + m * 16 + l16) * 32 + lq * 8]);
    #pragma unroll
    for (int n = 0; n < 2; ++n)
      bf[n] = u2b8(*(const u16x8*)&sB[cur][(wc * 32 + n * 16 + l16) * 32 + lq * 8]);
    __builtin_amdgcn_s_setprio(1);
    #pragma unroll
    for (int m = 0; m < 2; ++m)
      #pragma unroll
      for (int n = 0; n < 2; ++n)
        acc[m][n] = __builtin_amdgcn_mfma_f32_16x16x32_bf16(af[m], bf[n], acc[m][n], 0, 0, 0);
    __builtin_amdgcn_s_setprio(0);

    cur = (cur + 1 == 3) ? 0 : cur + 1;
  }
#undef GSTAGE64

  // C/D layout: col = lane&15, row = (lane>>4)*4 + reg
  #pragma unroll
  for (int m = 0; m < 2; ++m)
    #pragma unroll
    for (int n = 0; n < 2; ++n) {
      int row = rowBase + wr * 32 + m * 16 + lq * 4;
      int col = colBase + wc * 32 + n * 16 + l16;
      #pragma unroll
      for (int j = 0; j < 4; ++j)
        Cm[(size_t)(row + j) * N + col] = acc[m][n][j];
    }
}

// ------------------------- MFMA flash attention ----------------------------
// R9 config (proven fastest): 16 q-rows/wave, grid (32,32) descending, swapped
// QK^T, in-register P via k-slot permutation (V rows staged bit-permuted
// vrow=[b5 b2 b4 b3 b1 b0] so PV A-operand = own exp2'd registers), K staged
// by global_load_lds DMA into linear [64][64] with chunk swizzle (slot (r,c)
// holds chunk c^(r&7)), double buffer, T14 prefetch, ONE barrier per tile.
__global__ __launch_bounds__(256, 4) void attn_mfma_kernel(const u16* __restrict__ qr,
                                                           const u16* __restrict__ kr,
                                                           const u16* __restrict__ vr,
                                                           u16* __restrict__ ao) {
  constexpr int LDVT = 72;
  __shared__ u16 sK[2][64 * 64];                 // linear, chunk-swizzled
  __shared__ u16 sVt[2][64 * LDVT];              // sVt[buf][d][k-slot]

  const int tid = threadIdx.x;
  const int lane = tid & 63;
  const int w = tid >> 6;
  const int l16 = lane & 15, lq = lane >> 4;
  const int bh = blockIdx.x;
  const int qt = (int)gridDim.y - 1 - (int)blockIdx.y;   // long blocks first
  const int qbase = qt * 64;
  const size_t hb = (size_t)bh * (T_ * D_);

  // Q frags (pre-scaled bf16): rows qbase + w*16 + l16
  bf16x8 qv[2];
  #pragma unroll
  for (int dc = 0; dc < 2; ++dc) {
    int row = qbase + w * 16 + l16;
    qv[dc] = u2b8(*(const u16x8*)(qr + hb + (size_t)row * 64 + dc * 32 + lq * 8));
  }

  f32x4 o[4] = {};              // o[dt]: O[q=lq*4+j][d=dt*16+l16]
  float mrow = -1e30f;          // running max (log2 domain), row q=l16
  float lrow = 0.0f;            // per-lane partial denom, row q=l16

  // K DMA maps: wave w covers rows w*16 + s*8 + (lane>>3), chunk lane&7.
  const int krow0 = w * 16 + (lane >> 3);
  const int ksrc = ((lane & 7) ^ (lane >> 3)) * 8;   // elem offset in row
  // V staging maps (reg path)
  const int vkp = tid & 31;           // V slot-pair 0..31 (slots 2vkp, 2vkp+1)
  const int vdb = tid >> 5;           // V d-block 0..7
  const int vtr = ((vkp >> 4) & 1) * 32 + ((vkp >> 1) & 1) * 16 +
                  ((vkp >> 3) & 1) * 8 + ((vkp >> 2) & 1) * 4 + (vkp & 1) * 2;

  u16x8 rv0, rv1;
#define STAGEK(buf, k0s)                                                       \
  {                                                                            \
    _Pragma("unroll")                                                          \
    for (int s = 0; s < 2; ++s)                                                \
      __builtin_amdgcn_global_load_lds(                                        \
          (const AS1 u32*)(kr + hb + (size_t)((k0s) + krow0 + s * 8) * 64 + ksrc), \
          (AS3 u32*)&sK[buf][(w * 16 + s * 8) * 64], 16, 0, 0);                \
  }
#define LOADV(k0s)                                                             \
  {                                                                            \
    rv0 = *(const u16x8*)(vr + hb + (size_t)((k0s) + vtr) * 64 + vdb * 8);     \
    rv1 = *(const u16x8*)(vr + hb + (size_t)((k0s) + vtr + 1) * 64 + vdb * 8); \
  }
#define WRITEV(buf)                                                            \
  {                                                                            \
    _Pragma("unroll")                                                          \
    for (int u = 0; u < 8; ++u) {                                              \
      u16x2 pk; pk[0] = rv0[u]; pk[1] = rv1[u];                                \
      *(u16x2*)&sVt[buf][(vdb * 8 + u) * LDVT + 2 * vkp] = pk;                 \
    }                                                                          \
  }

  STAGEK(0, 0);
  LOADV(0);
  WRITEV(0);
  __syncthreads();               // drains vmcnt (K DMA) + LDS writes

  const int nt = qt + 1;
  int cur = 0;
  for (int it = 0; it < nt; ++it) {
    const int k0 = it * 64;
    const bool more = (it + 1 < nt);
    if (more) {
      STAGEK(cur ^ 1, k0 + 64);        // async DMA into other buffer
      LOADV(k0 + 64);                  // V prefetch into regs (T14)
    }

    // ---- QK^T (swapped): accs[kt][j] = S[q=l16][slot k0+kt*16+lq*4+j]
    f32x4 accs[4] = {};
    __builtin_amdgcn_s_setprio(1);
    #pragma unroll
    for (int kt = 0; kt < 4; ++kt) {
      int chy = ((lq) ^ (l16 & 7)) * 8;        // dc=0 chunk
      int chz = ((4 + lq) ^ (l16 & 7)) * 8;    // dc=1 chunk
      bf16x8 kf0 = u2b8(*(const u16x8*)&sK[cur][(kt * 16 + l16) * 64 + chy]);
      bf16x8 kf1 = u2b8(*(const u16x8*)&sK[cur][(kt * 16 + l16) * 64 + chz]);
      accs[kt] = __builtin_amdgcn_mfma_f32_16x16x32_bf16(kf0, qv[0], accs[kt], 0, 0, 0);
      accs[kt] = __builtin_amdgcn_mfma_f32_16x16x32_bf16(kf1, qv[1], accs[kt], 0, 0, 0);
    }
    __builtin_amdgcn_s_setprio(0);

    const int qrow = qbase + w * 16 + l16;
    if (k0 + 63 > qbase + w * 16) {      // wave-uniform: diagonal tile only
      #pragma unroll
      for (int kt = 0; kt < 4; ++kt)
        #pragma unroll
        for (int j = 0; j < 4; ++j)
          if (k0 + kt * 16 + lq * 4 + j > qrow) accs[kt][j] = -1e30f;
    }
    // row max for q=l16: depth-4 tree + 2 shfl (k spread across lq groups)
    float m0 = fmaxf(fmaxf(accs[0][0], accs[0][1]), fmaxf(accs[0][2], accs[0][3]));
    float m1 = fmaxf(fmaxf(accs[1][0], accs[1][1]), fmaxf(accs[1][2], accs[1][3]));
    float m2 = fmaxf(fmaxf(accs[2][0], accs[2][1]), fmaxf(accs[2][2], accs[2][3]));
    float m3 = fmaxf(fmaxf(accs[3][0], accs[3][1]), fmaxf(accs[3][2], accs[3][3]));
    float mx = fmaxf(fmaxf(m0, m1), fmaxf(m2, m3));
    mx = fmaxf(mx, __shfl_xor(mx, 16));
    mx = fmaxf(mx, __shfl_xor(mx, 32));

    if (!__all(mx <= mrow)) {            // defer-max: exact skip when no new max
      float mnew = fmaxf(mrow, mx);
      float corr = __builtin_amdgcn_exp2f(mrow - mnew);   // row q=l16
      lrow *= corr;
      mrow = mnew;
      // broadcast corr into D-row space (q=lq*4+j) before scaling O
      f32x4 corrv;
      #pragma unroll
      for (int j = 0; j < 4; ++j) corrv[j] = __shfl(corr, lq * 4 + j);
      #pragma unroll
      for (int dt = 0; dt < 4; ++dt) o[dt] *= corrv;
    }
    const float mu = mrow;
    // exp2 + pack: pb[kc][u] : u<4 <- slot kt=2kc, u>=4 <- kt=2kc+1
    bf16x8 pb[2];
    float lsum = 0.0f;
    #pragma unroll
    for (int kt = 0; kt < 4; ++kt) {
      #pragma unroll
      for (int j = 0; j < 4; ++j) {
        float p = __builtin_amdgcn_exp2f(accs[kt][j] - mu);
        lsum += p;
        pb[kt >> 1][(kt & 1) * 4 + j] = (__bf16)p;   // -> v_cvt_pk_bf16_f32
      }
    }
    lrow += lsum;

    // ---- PV: A-operand = own registers (slot perm); B from sVt ----
    __builtin_amdgcn_s_setprio(1);
    #pragma unroll
    for (int kc = 0; kc < 2; ++kc) {
      #pragma unroll
      for (int dt = 0; dt < 4; ++dt) {
        bf16x8 vt = u2b8(*(const u16x8*)&sVt[cur][(dt * 16 + l16) * LDVT + kc * 32 + lq * 8]);
        o[dt] = __builtin_amdgcn_mfma_f32_16x16x32_bf16(pb[kc], vt, o[dt], 0, 0, 0);
      }
    }
    __builtin_amdgcn_s_setprio(0);

    if (more) WRITEV(cur ^ 1);           // V^T into other buffer (reads were cur)
    __syncthreads();                     // one barrier/tile; drains K DMA too
    cur ^= 1;
  }

  // finalize: full row denom in l16-space, broadcast 1/l into D-row space.
  const int b = bh >> 4, h = bh & 15;
  float l = lrow;
  l += __shfl_xor(l, 16);
  l += __shfl_xor(l, 32);
  float linv = 1.0f / l;
  #pragma unroll
  for (int j = 0; j < 4; ++j) {
    float lj = __shfl(linv, lq * 4 + j);   // lane r (r<16) holds row r's denom
    int row = qbase + w * 16 + lq * 4 + j;
    u16* orow = ao + ((size_t)(b * T_ + row)) * C_ + h * 64;
    #pragma unroll
    for (int dt = 0; dt < 4; ++dt)
      orow[dt * 16 + l16] = f2b(o[dt][j] * lj);
  }
}

// ------------------------------- launcher ----------------------------------
// ws layout (bytes):                              size
//   xb     @ 0           bf16 x           8,388,608
//   wqkvT  @ 8388608     bf16 w_qkv^T     6,291,456
//   woutT  @ 14680064    bf16 w_out^T     2,097,152
//   qr     @ 41943040    bf16 [B,H,T,D]   8,388,608
//   kr     @ 50331648                     8,388,608
//   vr     @ 58720256                     8,388,608
//   ao     @ 67108864    bf16 attn out    8,388,608
//   csT    @ 75497472    f32x2 rope tbl     524,288
extern "C" void kernel_launch(void* const* d_in, const int* in_sizes, int n_in,
                              void* d_out, int out_size, void* d_ws, size_t ws_size,
                              hipStream_t stream) {
  const float* x     = (const float*)d_in[0];
  const float* w_qkv = (const float*)d_in[1];
  const float* w_out = (const float*)d_in[2];
  float* out = (float*)d_out;
  char* ws = (char*)d_ws;

  u16* xb     = (u16*)(ws + 0);
  u16* wqkvT  = (u16*)(ws + 8388608);
  u16* woutT  = (u16*)(ws + 14680064);
  u16* qr     = (u16*)(ws + 41943040);
  u16* kr     = (u16*)(ws + 50331648);
  u16* vr     = (u16*)(ws + 58720256);
  u16* ao     = (u16*)(ws + 67108864);
  float2* csT = (float2*)(ws + 75497472);

  prep_kernel<<<8448, 256, 0, stream>>>(x, w_qkv, w_out, xb, wqkvT, woutT, csT);
  gemm_bt_kernel<2><<<dim3(F_ / 128, M_ / 128), 256, 0, stream>>>(
      xb, wqkvT, nullptr, qr, kr, vr, (const float2*)csT, M_, F_, C_);
  attn_mfma_kernel<<<dim3(B_ * H_, T_ / 64), 256, 0, stream>>>(qr, kr, vr, ao);
  gemm64_kernel<<<dim3(C_ / 64, M_ / 64), 256, 0, stream>>>(ao, woutT, out, M_, C_, C_);
}

// Round 20
// 121.233 us; speedup vs baseline: 1.1095x; 1.0040x over previous
//
#include <hip/hip_runtime.h>
#include <stdint.h>

// ---------------------------------------------------------------------------
// MultiHeadSelfAttention: x(2,2048,1024) fp32, w_qkv(1024,3072), w_out(1024,1024)
// R19: R18 config + pair-row XOR swizzle on BOTH GEMM LDS tiles. The [*][32]
// fragment read was an 8-way bank conflict (row=64B=16 banks: even/odd l16
// lanes share one 4-bank window; 3.1M conflict-cyc/dispatch). Fix: treat tile
// as 64-elem pair-rows (8 x 16B slots); slot s of pair-row r' holds chunk
// s^(r'&7) (pre-swizzled DMA source, m231 both-sides rule); read slot
// ((R&1)*4+lq)^(R'&7). Pair-row stride 128B = 32 banks -> bank = slot only;
// 2 lanes/slot = 2-way = free (m136). Everything else identical to R18.
// ---------------------------------------------------------------------------

#define B_ 2
#define T_ 2048
#define C_ 1024
#define H_ 16
#define D_ 64
#define F_ 3072
#define M_ 4096

typedef unsigned short u16;
typedef unsigned int u32;
typedef u16 u16x2 __attribute__((ext_vector_type(2)));
typedef u16 u16x4 __attribute__((ext_vector_type(4)));
typedef u16 u16x8 __attribute__((ext_vector_type(8)));
typedef __bf16 bf16x8 __attribute__((ext_vector_type(8)));
typedef float f32x4 __attribute__((ext_vector_type(4)));

#define AS1 __attribute__((address_space(1)))
#define AS3 __attribute__((address_space(3)))

__device__ __forceinline__ float b2f(u16 u) {
  union { unsigned int i; float f; } v; v.i = ((unsigned int)u) << 16; return v.f;
}
__device__ __forceinline__ u16 f2b(float f) {  // RNE, finite inputs
  unsigned int u = __float_as_uint(f);
  u += 0x7fffu + ((u >> 16) & 1u);
  return (u16)(u >> 16);
}
__device__ __forceinline__ bf16x8 u2b8(u16x8 v) {
  union { u16x8 u; bf16x8 b; } x; x.u = v; return x.b;
}

// ----------------------------- fused prep kernel ---------------------------
// grid 8448 x 256: [0,4096) cast_x | [4096,7168) transpose w_qkv |
// [7168,8192) transpose w_out | [8192,8448) rope cos/sin table.
__global__ __launch_bounds__(256) void prep_kernel(const float* __restrict__ x,
                                                   const float* __restrict__ w_qkv,
                                                   const float* __restrict__ w_out,
                                                   u16* __restrict__ xb,
                                                   u16* __restrict__ wqkvT,
                                                   u16* __restrict__ woutT,
                                                   float2* __restrict__ csT) {
  __shared__ float tile[32][33];
  const int bid = blockIdx.x;
  const int tid = threadIdx.x;

  if (bid < 4096) {                       // ---- cast_x: fp32 -> bf16 ----
    int i = bid * 256 + tid;              // M_*C_/4 elems of float4
    float4 v = ((const float4*)x)[i];
    u16x4 r;
    r[0] = f2b(v.x); r[1] = f2b(v.y); r[2] = f2b(v.z); r[3] = f2b(v.w);
    ((u16x4*)xb)[i] = r;
  } else if (bid < 8192) {                // ---- transpose_cast w_qkv / w_out
    const float* in;  u16* out;  int R, Ccol, b;
    if (bid < 7168) { in = w_qkv; out = wqkvT; R = C_; Ccol = F_; b = bid - 4096; }
    else            { in = w_out; out = woutT; R = C_; Ccol = C_; b = bid - 7168; }
    int nbx = Ccol / 32;
    int c0 = (b % nbx) * 32, r0 = (b / nbx) * 32;
    int tx = tid & 31, ty = tid >> 5;     // ty = 0..7
    #pragma unroll
    for (int i = 0; i < 32; i += 8)
      tile[ty + i][tx] = in[(size_t)(r0 + ty + i) * Ccol + c0 + tx];
    __syncthreads();
    #pragma unroll
    for (int i = 0; i < 32; i += 8)
      out[(size_t)(c0 + ty + i) * R + r0 + tx] = f2b(tile[tx][ty + i]);
  } else {                                // ---- rope table ----
    int idx = (bid - 8192) * 256 + tid;   // T_*32 entries
    int t = idx >> 5, i = idx & 31;
    float inv_freq = powf(10000.0f, -(float)(2 * i) / 64.0f);
    float ang = (float)t * inv_freq;
    csT[idx] = make_float2(cosf(ang), sinf(ang));
  }
}

// ------------------------------- MFMA GEMM (128^2) -------------------------
// C[M,N] = A[M,K] * Bt[N,K]^T, bf16 in. 128x128 tile, BK=32, 4 waves, 4x4
// frags, global_load_lds(16), 3-buffer distance-2 pipeline, XCD swizzle.
// LDS tile viewed as 64 pair-rows x 8 slots (16B); slot s of pair-row r'
// holds logical chunk s^(r'&7) via pre-swizzled DMA source; fragment read at
// slot ((R&1)*4+lq)^(R'&7) -> 2-way bank access (free).
// MODE 0: float out. MODE 2: RoPE epilogue + scatter to qr/kr/vr.
template <int MODE>
__global__ __launch_bounds__(256) void gemm_bt_kernel(const u16* __restrict__ A,
                                                      const u16* __restrict__ Bt,
                                                      float* __restrict__ Cm,
                                                      u16* __restrict__ qr,
                                                      u16* __restrict__ kr,
                                                      u16* __restrict__ vrp,
                                                      const float2* __restrict__ csT,
                                                      int M, int N, int K) {
  __shared__ u16 sA[3][128 * 32];
  __shared__ u16 sB[3][128 * 32];
  const int tid = threadIdx.x;
  const int lane = tid & 63;
  const int wv = tid >> 6;
  const int wr = wv >> 1, wc = wv & 1;
  const int l16 = lane & 15, lq = lane >> 4;

  const int gx = gridDim.x;
  const int nwg = gx * gridDim.y;
  const int flat = blockIdx.y * gx + blockIdx.x;
  const int swz = (flat & 7) * (nwg >> 3) + (flat >> 3);
  const int rowBase = (swz / gx) * 128;
  const int colBase = (swz % gx) * 128;

  f32x4 acc[4][4] = {};

  // Staging (per s-phase): dest 16B-chunk D = wv*128 + s*64 + lane.
  // Pair-row r' = D>>3, slot = D&7, logical ch = slot^(r'&7):
  //   global row R = 2r' + (ch>>2), elem col = (ch&3)*8.
#define GSTAGE(buf, kk)                                                          \
  {                                                                              \
    _Pragma("unroll")                                                            \
    for (int s = 0; s < 2; ++s) {                                                \
      int D = wv * 128 + s * 64 + lane;                                          \
      int rp = D >> 3, ch = (D & 7) ^ (rp & 7);                                  \
      int r = 2 * rp + (ch >> 2), ccc = (ch & 3) * 8;                            \
      __builtin_amdgcn_global_load_lds(                                          \
          (const AS1 u32*)(A + (size_t)(rowBase + r) * K + (kk) + ccc),          \
          (AS3 u32*)&sA[buf][D * 8], 16, 0, 0);                                  \
      __builtin_amdgcn_global_load_lds(                                          \
          (const AS1 u32*)(Bt + (size_t)(colBase + r) * K + (kk) + ccc),         \
          (AS3 u32*)&sB[buf][D * 8], 16, 0, 0);                                  \
    }                                                                            \
  }
  // Fragment read: row R -> elem addr (R>>1)*64 + (((R&1)*4+lq)^((R>>1)&7))*8
#define FRADDR(R) ((((R) >> 1) << 6) + (((((R) & 1) * 4 + lq) ^ (((R) >> 1) & 7)) << 3))

  const int NT = K >> 5;                 // K/32 tiles
  GSTAGE(0, 0);
  if (NT > 1) GSTAGE(1, 32);

  int cur = 0;
  for (int kt = 0; kt < NT; ++kt) {
    if (kt + 1 < NT) {
      asm volatile("s_waitcnt vmcnt(4)" ::: "memory");   // tile kt landed (own)
    } else {
      asm volatile("s_waitcnt vmcnt(0)" ::: "memory");   // final tile
    }
    __builtin_amdgcn_s_barrier();        // tile kt visible; kt-1 reads done

    if (kt + 2 < NT) {
      int nb = cur + 2; if (nb >= 3) nb -= 3;
      GSTAGE(nb, (kt + 2) * 32);         // overlaps this iter's compute
    }

    bf16x8 af[4], bf[4];
    #pragma unroll
    for (int m = 0; m < 4; ++m)
      af[m] = u2b8(*(const u16x8*)&sA[cur][FRADDR(wr * 64 + m * 16 + l16)]);
    #pragma unroll
    for (int n = 0; n < 4; ++n)
      bf[n] = u2b8(*(const u16x8*)&sB[cur][FRADDR(wc * 64 + n * 16 + l16)]);
    __builtin_amdgcn_s_setprio(1);
    #pragma unroll
    for (int m = 0; m < 4; ++m)
      #pragma unroll
      for (int n = 0; n < 4; ++n)
        acc[m][n] = __builtin_amdgcn_mfma_f32_16x16x32_bf16(af[m], bf[n], acc[m][n], 0, 0, 0);
    __builtin_amdgcn_s_setprio(0);

    cur = (cur + 1 == 3) ? 0 : cur + 1;
  }
#undef GSTAGE

  // C/D layout (verified m89): col = lane&15, row = (lane>>4)*4 + reg
  if constexpr (MODE == 0) {
    #pragma unroll
    for (int m = 0; m < 4; ++m)
      #pragma unroll
      for (int n = 0; n < 4; ++n) {
        int row = rowBase + wr * 64 + m * 16 + lq * 4;
        int col = colBase + wc * 64 + n * 16 + l16;
        #pragma unroll
        for (int j = 0; j < 4; ++j)
          Cm[(size_t)(row + j) * N + col] = acc[m][n][j];
      }
  } else {
    // which: 0=q 1=k 2=v (block-uniform); head: uniform per (wave,n-range)
    const int which = colBase >> 10;
    const int head = ((colBase + wc * 64) >> 6) & 15;
    const float QSC = 0.125f * 1.44269504f;
    u16* const dst = (which == 0) ? qr : (which == 1) ? kr : vrp;
    #pragma unroll
    for (int m = 0; m < 4; ++m) {
      #pragma unroll
      for (int n = 0; n < 4; ++n) {
        const int d0 = n * 16 + l16;           // d within head (0..63)
        #pragma unroll
        for (int j = 0; j < 4; ++j) {
          int row = rowBase + wr * 64 + m * 16 + lq * 4 + j;
          int b = row >> 11, t = row & 2047;
          float v = acc[m][n][j];
          u16 outv;
          if (which == 2) {
            outv = f2b(v);
          } else {
            float p = __shfl_xor(v, 1);        // RoPE partner (d0^1)
            float2 cs = csT[t * 32 + (d0 >> 1)];
            float r = (l16 & 1) ? fmaf(p, cs.y, v * cs.x)    // odd:  xe*s + xo*c
                                : fmaf(-p, cs.y, v * cs.x);  // even: xe*c - xo*s
            if (which == 0) r *= QSC;
            outv = f2b(r);
          }
          dst[((size_t)(b * 16 + head) * 2048 + t) * 64 + d0] = outv;
        }
      }
    }
  }
}

// --------------------------- MFMA GEMM (64^2, out-proj) --------------------
// 64x64 tile, BK=32, 4 waves (2x2), distance-2 / 3-buffer / vmcnt(2),
// grid (16,64)=1024 = 4 blocks/CU, XCD swizzle. Same pair-row slot swizzle.
__global__ __launch_bounds__(256) void gemm64_kernel(const u16* __restrict__ A,
                                                     const u16* __restrict__ Bt,
                                                     float* __restrict__ Cm,
                                                     int M, int N, int K) {
  __shared__ u16 sA[3][64 * 32];
  __shared__ u16 sB[3][64 * 32];
  const int tid = threadIdx.x;
  const int lane = tid & 63;
  const int wv = tid >> 6;
  const int wr = wv >> 1, wc = wv & 1;
  const int l16 = lane & 15, lq = lane >> 4;

  const int gx = gridDim.x;
  const int nwg = gx * gridDim.y;
  const int flat = blockIdx.y * gx + blockIdx.x;
  const int swz = (flat & 7) * (nwg >> 3) + (flat >> 3);
  const int rowBase = (swz / gx) * 64;
  const int colBase = (swz % gx) * 64;

  f32x4 acc[2][2] = {};

#define GSTAGE64(buf, kk)                                                        \
  {                                                                              \
    int D = wv * 64 + lane;                                                      \
    int rp = D >> 3, ch = (D & 7) ^ (rp & 7);                                    \
    int r = 2 * rp + (ch >> 2), ccc = (ch & 3) * 8;                              \
    __builtin_amdgcn_global_load_lds(                                            \
        (const AS1 u32*)(A + (size_t)(rowBase + r) * K + (kk) + ccc),            \
        (AS3 u32*)&sA[buf][D * 8], 16, 0, 0);                                    \
    __builtin_amdgcn_global_load_lds(                                            \
        (const AS1 u32*)(Bt + (size_t)(colBase + r) * K + (kk) + ccc),           \
        (AS3 u32*)&sB[buf][D * 8], 16, 0, 0);                                    \
  }

  const int NT = K >> 5;                 // K/32 tiles
  GSTAGE64(0, 0);
  if (NT > 1) GSTAGE64(1, 32);

  int cur = 0;
  for (int kt = 0; kt < NT; ++kt) {
    if (kt + 1 < NT) {
      asm volatile("s_waitcnt vmcnt(2)" ::: "memory");   // tile kt landed (own 2)
    } else {
      asm volatile("s_waitcnt vmcnt(0)" ::: "memory");   // final tile
    }
    __builtin_amdgcn_s_barrier();        // tile kt visible; kt-1 reads done

    if (kt + 2 < NT) {
      int nb = cur + 2; if (nb >= 3) nb -= 3;
      GSTAGE64(nb, (kt + 2) * 32);       // overlaps this iter's compute
    }

    bf16x8 af[2], bf[2];
    #pragma unroll
    for (int m = 0; m < 2; ++m)
      af[m] = u2b8(*(const u16x8*)&sA[cur][FRADDR(wr * 32 + m * 16 + l16)]);
    #pragma unroll
    for (int n = 0; n < 2; ++n)
      bf[n] = u2b8(*(const u16x8*)&sB[cur][FRADDR(wc * 32 + n * 16 + l16)]);
    __builtin_amdgcn_s_setprio(1);
    #pragma unroll
    for (int m = 0; m < 2; ++m)
      #pragma unroll
      for (int n = 0; n < 2; ++n)
        acc[m][n] = __builtin_amdgcn_mfma_f32_16x16x32_bf16(af[m], bf[n], acc[m][n], 0, 0, 0);
    __builtin_amdgcn_s_setprio(0);

    cur = (cur + 1 == 3) ? 0 : cur + 1;
  }
#undef GSTAGE64

  // C/D layout: col = lane&15, row = (lane>>4)*4 + reg
  #pragma unroll
  for (int m = 0; m < 2; ++m)
    #pragma unroll
    for (int n = 0; n < 2; ++n) {
      int row = rowBase + wr * 32 + m * 16 + lq * 4;
      int col = colBase + wc * 32 + n * 16 + l16;
      #pragma unroll
      for (int j = 0; j < 4; ++j)
        Cm[(size_t)(row + j) * N + col] = acc[m][n][j];
    }
}

// ------------------------- MFMA flash attention ----------------------------
// R9 config (proven fastest): 16 q-rows/wave, grid (32,32) descending, swapped
// QK^T, in-register P via k-slot permutation (V rows staged bit-permuted
// vrow=[b5 b2 b4 b3 b1 b0] so PV A-operand = own exp2'd registers), K staged
// by global_load_lds DMA into linear [64][64] with chunk swizzle (slot (r,c)
// holds chunk c^(r&7)), double buffer, T14 prefetch, ONE barrier per tile.
__global__ __launch_bounds__(256, 4) void attn_mfma_kernel(const u16* __restrict__ qr,
                                                           const u16* __restrict__ kr,
                                                           const u16* __restrict__ vr,
                                                           u16* __restrict__ ao) {
  constexpr int LDVT = 72;
  __shared__ u16 sK[2][64 * 64];                 // linear, chunk-swizzled
  __shared__ u16 sVt[2][64 * LDVT];              // sVt[buf][d][k-slot]

  const int tid = threadIdx.x;
  const int lane = tid & 63;
  const int w = tid >> 6;
  const int l16 = lane & 15, lq = lane >> 4;
  const int bh = blockIdx.x;
  const int qt = (int)gridDim.y - 1 - (int)blockIdx.y;   // long blocks first
  const int qbase = qt * 64;
  const size_t hb = (size_t)bh * (T_ * D_);

  // Q frags (pre-scaled bf16): rows qbase + w*16 + l16
  bf16x8 qv[2];
  #pragma unroll
  for (int dc = 0; dc < 2; ++dc) {
    int row = qbase + w * 16 + l16;
    qv[dc] = u2b8(*(const u16x8*)(qr + hb + (size_t)row * 64 + dc * 32 + lq * 8));
  }

  f32x4 o[4] = {};              // o[dt]: O[q=lq*4+j][d=dt*16+l16]
  float mrow = -1e30f;          // running max (log2 domain), row q=l16
  float lrow = 0.0f;            // per-lane partial denom, row q=l16

  // K DMA maps: wave w covers rows w*16 + s*8 + (lane>>3), chunk lane&7.
  const int krow0 = w * 16 + (lane >> 3);
  const int ksrc = ((lane & 7) ^ (lane >> 3)) * 8;   // elem offset in row
  // V staging maps (reg path)
  const int vkp = tid & 31;           // V slot-pair 0..31 (slots 2vkp, 2vkp+1)
  const int vdb = tid >> 5;           // V d-block 0..7
  const int vtr = ((vkp >> 4) & 1) * 32 + ((vkp >> 1) & 1) * 16 +
                  ((vkp >> 3) & 1) * 8 + ((vkp >> 2) & 1) * 4 + (vkp & 1) * 2;

  u16x8 rv0, rv1;
#define STAGEK(buf, k0s)                                                       \
  {                                                                            \
    _Pragma("unroll")                                                          \
    for (int s = 0; s < 2; ++s)                                                \
      __builtin_amdgcn_global_load_lds(                                        \
          (const AS1 u32*)(kr + hb + (size_t)((k0s) + krow0 + s * 8) * 64 + ksrc), \
          (AS3 u32*)&sK[buf][(w * 16 + s * 8) * 64], 16, 0, 0);                \
  }
#define LOADV(k0s)                                                             \
  {                                                                            \
    rv0 = *(const u16x8*)(vr + hb + (size_t)((k0s) + vtr) * 64 + vdb * 8);     \
    rv1 = *(const u16x8*)(vr + hb + (size_t)((k0s) + vtr + 1) * 64 + vdb * 8); \
  }
#define WRITEV(buf)                                                            \
  {                                                                            \
    _Pragma("unroll")                                                          \
    for (int u = 0; u < 8; ++u) {                                              \
      u16x2 pk; pk[0] = rv0[u]; pk[1] = rv1[u];                                \
      *(u16x2*)&sVt[buf][(vdb * 8 + u) * LDVT + 2 * vkp] = pk;                 \
    }                                                                          \
  }

  STAGEK(0, 0);
  LOADV(0);
  WRITEV(0);
  __syncthreads();               // drains vmcnt (K DMA) + LDS writes

  const int nt = qt + 1;
  int cur = 0;
  for (int it = 0; it < nt; ++it) {
    const int k0 = it * 64;
    const bool more = (it + 1 < nt);
    if (more) {
      STAGEK(cur ^ 1, k0 + 64);        // async DMA into other buffer
      LOADV(k0 + 64);                  // V prefetch into regs (T14)
    }

    // ---- QK^T (swapped): accs[kt][j] = S[q=l16][slot k0+kt*16+lq*4+j]
    f32x4 accs[4] = {};
    __builtin_amdgcn_s_setprio(1);
    #pragma unroll
    for (int kt = 0; kt < 4; ++kt) {
      int chy = ((lq) ^ (l16 & 7)) * 8;        // dc=0 chunk
      int chz = ((4 + lq) ^ (l16 & 7)) * 8;    // dc=1 chunk
      bf16x8 kf0 = u2b8(*(const u16x8*)&sK[cur][(kt * 16 + l16) * 64 + chy]);
      bf16x8 kf1 = u2b8(*(const u16x8*)&sK[cur][(kt * 16 + l16) * 64 + chz]);
      accs[kt] = __builtin_amdgcn_mfma_f32_16x16x32_bf16(kf0, qv[0], accs[kt], 0, 0, 0);
      accs[kt] = __builtin_amdgcn_mfma_f32_16x16x32_bf16(kf1, qv[1], accs[kt], 0, 0, 0);
    }
    __builtin_amdgcn_s_setprio(0);

    const int qrow = qbase + w * 16 + l16;
    if (k0 + 63 > qbase + w * 16) {      // wave-uniform: diagonal tile only
      #pragma unroll
      for (int kt = 0; kt < 4; ++kt)
        #pragma unroll
        for (int j = 0; j < 4; ++j)
          if (k0 + kt * 16 + lq * 4 + j > qrow) accs[kt][j] = -1e30f;
    }
    // row max for q=l16: depth-4 tree + 2 shfl (k spread across lq groups)
    float m0 = fmaxf(fmaxf(accs[0][0], accs[0][1]), fmaxf(accs[0][2], accs[0][3]));
    float m1 = fmaxf(fmaxf(accs[1][0], accs[1][1]), fmaxf(accs[1][2], accs[1][3]));
    float m2 = fmaxf(fmaxf(accs[2][0], accs[2][1]), fmaxf(accs[2][2], accs[2][3]));
    float m3 = fmaxf(fmaxf(accs[3][0], accs[3][1]), fmaxf(accs[3][2], accs[3][3]));
    float mx = fmaxf(fmaxf(m0, m1), fmaxf(m2, m3));
    mx = fmaxf(mx, __shfl_xor(mx, 16));
    mx = fmaxf(mx, __shfl_xor(mx, 32));

    if (!__all(mx <= mrow)) {            // defer-max: exact skip when no new max
      float mnew = fmaxf(mrow, mx);
      float corr = __builtin_amdgcn_exp2f(mrow - mnew);   // row q=l16
      lrow *= corr;
      mrow = mnew;
      // broadcast corr into D-row space (q=lq*4+j) before scaling O
      f32x4 corrv;
      #pragma unroll
      for (int j = 0; j < 4; ++j) corrv[j] = __shfl(corr, lq * 4 + j);
      #pragma unroll
      for (int dt = 0; dt < 4; ++dt) o[dt] *= corrv;
    }
    const float mu = mrow;
    // exp2 + pack: pb[kc][u] : u<4 <- slot kt=2kc, u>=4 <- kt=2kc+1
    bf16x8 pb[2];
    float lsum = 0.0f;
    #pragma unroll
    for (int kt = 0; kt < 4; ++kt) {
      #pragma unroll
      for (int j = 0; j < 4; ++j) {
        float p = __builtin_amdgcn_exp2f(accs[kt][j] - mu);
        lsum += p;
        pb[kt >> 1][(kt & 1) * 4 + j] = (__bf16)p;   // -> v_cvt_pk_bf16_f32
      }
    }
    lrow += lsum;

    // ---- PV: A-operand = own registers (slot perm); B from sVt ----
    __builtin_amdgcn_s_setprio(1);
    #pragma unroll
    for (int kc = 0; kc < 2; ++kc) {
      #pragma unroll
      for (int dt = 0; dt < 4; ++dt) {
        bf16x8 vt = u2b8(*(const u16x8*)&sVt[cur][(dt * 16 + l16) * LDVT + kc * 32 + lq * 8]);
        o[dt] = __builtin_amdgcn_mfma_f32_16x16x32_bf16(pb[kc], vt, o[dt], 0, 0, 0);
      }
    }
    __builtin_amdgcn_s_setprio(0);

    if (more) WRITEV(cur ^ 1);           // V^T into other buffer (reads were cur)
    __syncthreads();                     // one barrier/tile; drains K DMA too
    cur ^= 1;
  }

  // finalize: full row denom in l16-space, broadcast 1/l into D-row space.
  const int b = bh >> 4, h = bh & 15;
  float l = lrow;
  l += __shfl_xor(l, 16);
  l += __shfl_xor(l, 32);
  float linv = 1.0f / l;
  #pragma unroll
  for (int j = 0; j < 4; ++j) {
    float lj = __shfl(linv, lq * 4 + j);   // lane r (r<16) holds row r's denom
    int row = qbase + w * 16 + lq * 4 + j;
    u16* orow = ao + ((size_t)(b * T_ + row)) * C_ + h * 64;
    #pragma unroll
    for (int dt = 0; dt < 4; ++dt)
      orow[dt * 16 + l16] = f2b(o[dt][j] * lj);
  }
}

// ------------------------------- launcher ----------------------------------
// ws layout (bytes):                              size
//   xb     @ 0           bf16 x           8,388,608
//   wqkvT  @ 8388608     bf16 w_qkv^T     6,291,456
//   woutT  @ 14680064    bf16 w_out^T     2,097,152
//   qr     @ 41943040    bf16 [B,H,T,D]   8,388,608
//   kr     @ 50331648                     8,388,608
//   vr     @ 58720256                     8,388,608
//   ao     @ 67108864    bf16 attn out    8,388,608
//   csT    @ 75497472    f32x2 rope tbl     524,288
extern "C" void kernel_launch(void* const* d_in, const int* in_sizes, int n_in,
                              void* d_out, int out_size, void* d_ws, size_t ws_size,
                              hipStream_t stream) {
  const float* x     = (const float*)d_in[0];
  const float* w_qkv = (const float*)d_in[1];
  const float* w_out = (const float*)d_in[2];
  float* out = (float*)d_out;
  char* ws = (char*)d_ws;

  u16* xb     = (u16*)(ws + 0);
  u16* wqkvT  = (u16*)(ws + 8388608);
  u16* woutT  = (u16*)(ws + 14680064);
  u16* qr     = (u16*)(ws + 41943040);
  u16* kr     = (u16*)(ws + 50331648);
  u16* vr     = (u16*)(ws + 58720256);
  u16* ao     = (u16*)(ws + 67108864);
  float2* csT = (float2*)(ws + 75497472);

  prep_kernel<<<8448, 256, 0, stream>>>(x, w_qkv, w_out, xb, wqkvT, woutT, csT);
  gemm_bt_kernel<2><<<dim3(F_ / 128, M_ / 128), 256, 0, stream>>>(
      xb, wqkvT, nullptr, qr, kr, vr, (const float2*)csT, M_, F_, C_);
  attn_mfma_kernel<<<dim3(B_ * H_, T_ / 64), 256, 0, stream>>>(qr, kr, vr, ao);
  gemm64_kernel<<<dim3(C_ / 64, M_ / 64), 256, 0, stream>>>(ao, woutT, out, M_, C_, C_);
}